// Round 3
// baseline (465.648 us; speedup 1.0000x reference)
//
#include <hip/hip_runtime.h>
#include <cstdint>

#define NB    8
#define NSEQ  4096
#define CDIM  256
#define NTOK  (NB*NSEQ)

typedef _Float16 half8  __attribute__((ext_vector_type(8)));
typedef _Float16 half4v __attribute__((ext_vector_type(4)));
typedef float    f32x4  __attribute__((ext_vector_type(4)));

typedef unsigned int u32_g __attribute__((address_space(1)));
typedef unsigned int u32_l __attribute__((address_space(3)));

// direct global->LDS, 16B per lane (used by proj kernel only)
__device__ __forceinline__ void gload_lds16(const void* g, void* l) {
  __builtin_amdgcn_global_load_lds((u32_g*)(uintptr_t)g,
                                   (u32_l*)(uint32_t)(uintptr_t)l, 16, 0, 0);
}

__device__ __forceinline__ f32x4 vmax4(f32x4 a, f32x4 b) {
  f32x4 r;
  r[0] = fmaxf(a[0], b[0]); r[1] = fmaxf(a[1], b[1]);
  r[2] = fmaxf(a[2], b[2]); r[3] = fmaxf(a[3], b[3]);
  return r;
}

__device__ __forceinline__ f32x4 shfl_xor4(f32x4 v, int m) {
  f32x4 r;
  r[0] = __shfl_xor(v[0], m, 64); r[1] = __shfl_xor(v[1], m, 64);
  r[2] = __shfl_xor(v[2], m, 64); r[3] = __shfl_xor(v[3], m, 64);
  return r;
}

// ---------------- LayerNorm: one wave per token (C=256 = 64 lanes x float4)
__global__ __launch_bounds__(256) void ln_kernel(
    const float* __restrict__ x, const float* __restrict__ gam,
    const float* __restrict__ bet, float* __restrict__ xnf,
    _Float16* __restrict__ xnh) {
  const int lane = threadIdx.x & 63;
  const size_t tok = (size_t)blockIdx.x * 4 + (threadIdx.x >> 6);
  const float4 v = ((const float4*)(x + tok * CDIM))[lane];
  float s  = v.x + v.y + v.z + v.w;
  float s2 = v.x*v.x + v.y*v.y + v.z*v.z + v.w*v.w;
  #pragma unroll
  for (int m = 1; m < 64; m <<= 1) {
    s  += __shfl_xor(s,  m, 64);
    s2 += __shfl_xor(s2, m, 64);
  }
  const float mean = s * (1.0f / CDIM);
  const float rstd = rsqrtf(s2 * (1.0f / CDIM) - mean * mean + 1e-3f);
  const float4 gv = ((const float4*)gam)[lane];
  const float4 bv = ((const float4*)bet)[lane];
  float4 o;
  o.x = (v.x - mean) * rstd * gv.x + bv.x;
  o.y = (v.y - mean) * rstd * gv.y + bv.y;
  o.z = (v.z - mean) * rstd * gv.z + bv.z;
  o.w = (v.w - mean) * rstd * gv.w + bv.w;
  ((float4*)(xnf + tok * CDIM))[lane] = o;
  half4v h;
  h[0] = (_Float16)o.x; h[1] = (_Float16)o.y;
  h[2] = (_Float16)o.z; h[3] = (_Float16)o.w;
  ((half4v*)(xnh + tok * CDIM))[lane] = h;
}

// ---------------- projection GEMM (unchanged from R1)
__global__ __launch_bounds__(256, 2) void proj_kernel(
    const _Float16* __restrict__ inh,
    const float* __restrict__ wq_, const float* __restrict__ bq_,
    const float* __restrict__ wk_, const float* __restrict__ bk_,
    const float* __restrict__ wv_, const float* __restrict__ bv_,
    const float* __restrict__ wp_, const float* __restrict__ bp_,
    _Float16* __restrict__ qg, _Float16* __restrict__ kg, _Float16* __restrict__ vtg,
    const float* __restrict__ xnf, float* __restrict__ outf,
    int mode_base) {
  extern __shared__ char smem[];
  const int mode = mode_base + blockIdx.z;
  const float* wsel = (mode == 0) ? wq_ : (mode == 1) ? wk_ : (mode == 2) ? wv_ : wp_;
  const float* bsel = (mode == 0) ? bq_ : (mode == 1) ? bk_ : (mode == 2) ? bv_ : bp_;

  const int tid = threadIdx.x;
  const int lane = tid & 63;
  const int wid  = tid >> 6;     // 0..3
  const int g    = lane >> 4;    // 0..3
  const int lr   = lane & 15;
  const int jstrip = blockIdx.y; // 0..3
  const size_t tok0 = (size_t)blockIdx.x * 512;

  char* wt   = smem;             // [64 j][256 c] f16, XOR-swizzled (32KB)
  char* tile = smem + 32768;     // [64 tok][256 c] f16, swizzled (32KB)

  for (int i = 0; i < 64; ++i) {
    int idx = i * 256 + tid;
    int c = idx >> 6, j = idx & 63;
    float val = wsel[(size_t)c * CDIM + jstrip * 64 + j];
    *(_Float16*)(wt + j * 512 + ((((c >> 3) ^ (j & 7))) << 4) + ((c & 7) << 1)) =
        (_Float16)val;
  }
  float bjv[4];
  #pragma unroll
  for (int jc = 0; jc < 4; ++jc) bjv[jc] = bsel[jstrip * 64 + jc * 16 + lr];
  __syncthreads();

  for (int t = 0; t < 8; ++t) {
    const size_t trow0 = tok0 + t * 64;
    #pragma unroll
    for (int i = 0; i < 8; ++i) {
      int pbase = (i * 4 + wid) * 64;
      int p = pbase + lane;
      int row = p >> 5, sl = p & 31;
      gload_lds16(inh + (trow0 + row) * CDIM + (size_t)((sl ^ (row & 7)) * 8),
                  tile + pbase * 16);
    }
    __syncthreads();

    f32x4 acc[4] = {{0,0,0,0},{0,0,0,0},{0,0,0,0},{0,0,0,0}};
    #pragma unroll
    for (int kc = 0; kc < 8; ++kc) {
      half8 a = *(const half8*)(tile + (wid * 16 + lr) * 512 +
                                ((((kc << 2) | g) ^ (lr & 7)) << 4));
      #pragma unroll
      for (int jc = 0; jc < 4; ++jc) {
        half8 bf = *(const half8*)(wt + (jc * 16 + lr) * 512 +
                                   ((((kc << 2) | g) ^ (lr & 7)) << 4));
        acc[jc] = __builtin_amdgcn_mfma_f32_16x16x32_f16(a, bf, acc[jc], 0, 0, 0);
      }
    }

    if (mode == 3) {
      #pragma unroll
      for (int jc = 0; jc < 4; ++jc) {
        #pragma unroll
        for (int r = 0; r < 4; ++r) {
          size_t row = trow0 + wid * 16 + g * 4 + r;
          size_t off = row * CDIM + jstrip * 64 + jc * 16 + lr;
          outf[off] = acc[jc][r] + bjv[jc] + xnf[off];
        }
      }
    } else {
      const float csc = (mode == 0) ? 0.09016844005556021f : 1.0f; // log2(e)/16
      __syncthreads();
      _Float16* ot = (_Float16*)tile;  // [64][72]
      #pragma unroll
      for (int jc = 0; jc < 4; ++jc)
        #pragma unroll
        for (int r = 0; r < 4; ++r)
          ot[(wid * 16 + g * 4 + r) * 72 + jc * 16 + lr] =
              (_Float16)((acc[jc][r] + bjv[jc]) * csc);
      __syncthreads();
      if (mode != 2) {
        _Float16* dst = (mode == 0) ? qg : kg;
        #pragma unroll
        for (int it = 0; it < 2; ++it) {
          int s = it * 256 + tid;
          int row = s >> 3, sl = s & 7;
          half8 vv = *(const half8*)(ot + row * 72 + sl * 8);
          *(half8*)(dst + (trow0 + row) * CDIM + jstrip * 64 + sl * 8) = vv;
        }
      } else {
        #pragma unroll
        for (int it = 0; it < 2; ++it) {
          int s = it * 256 + tid;
          int j = s >> 3, ns = s & 7;
          half8 vv;
          #pragma unroll
          for (int e = 0; e < 8; ++e) vv[e] = ot[(ns * 8 + e) * 72 + j];
          size_t bb  = trow0 >> 12;
          size_t nin = (trow0 & 4095) + ns * 8;
          *(half8*)(vtg + ((size_t)bb * CDIM + jstrip * 64 + j) * NSEQ + nin) = vv;
        }
      }
    }
    __syncthreads();
  }
}

// ---------------- flash attention v2: QBLK=128, KVBLK=64, 8 waves
// LDS: K dbuf 2x32KB @0, V dbuf 2x32KB @65536, P 16KB @131072,
//      pmax 1KB @147456, psum 1KB @148480, alf 512B @149504
#define ATTN_LDS 150016

__global__ __launch_bounds__(512, 2) void attn_kernel(
    const _Float16* __restrict__ qg, const _Float16* __restrict__ kg,
    const _Float16* __restrict__ vtg, _Float16* __restrict__ og) {
  extern __shared__ char smem[];
  char*  pbuf  = smem + 131072;           // [128 q][8 slot][8 f16], swizzle f(row)=(row>>1)&7
  float* pmaxb = (float*)(smem + 147456); // [2 kvh][128 rows]
  float* psumb = (float*)(smem + 148480); // [2 kvh][128 rows]
  float* alf   = (float*)(smem + 149504); // [128]

  const int tid  = threadIdx.x;
  const int lane = tid & 63;
  const int wid  = tid >> 6;     // 0..7
  const int g    = lane >> 4;
  const int lr   = lane & 15;
  const int b    = blockIdx.x & 7;       // XCD-affine: batch pinned to one XCD's L2
  const int n0   = (blockIdx.x >> 3) * 128;
  // S roles: wave = 32q x 32kv
  const int qq   = wid >> 1;     // 0..3 (q 32-row group)
  const int kvh  = wid & 1;      // kv half
  // PV roles: wave = 64q x 64d
  const int qh   = wid & 1;
  const int dq   = wid >> 1;

  // Q fragments: 2 A-tiles x 8 kc (64 VGPR), scale*log2e pre-folded
  half8 qf[2][8];
  #pragma unroll
  for (int mi = 0; mi < 2; ++mi) {
    const _Float16* qp =
        qg + ((size_t)(b * NSEQ + n0 + qq * 32 + mi * 16 + lr)) * CDIM + g * 8;
    #pragma unroll
    for (int kc = 0; kc < 8; ++kc) qf[mi][kc] = *(const half8*)(qp + kc * 32);
  }

  f32x4 o[4][4];  // [mi2][dc]: rows qh*64+mi2*16+4g+r, cols dq*64+dc*16+lr
  #pragma unroll
  for (int mi = 0; mi < 4; ++mi)
    #pragma unroll
    for (int dc = 0; dc < 4; ++dc) o[mi][dc] = (f32x4){0,0,0,0};
  f32x4 mrow[2], lrow[2];
  #pragma unroll
  for (int mi = 0; mi < 2; ++mi) {
    mrow[mi] = (f32x4){-1e30f,-1e30f,-1e30f,-1e30f};
    lrow[mi] = (f32x4){0,0,0,0};
  }

  half8 kst[4], vst[4];
  // prologue: stage tile 0 into buffer 0
  #pragma unroll
  for (int i = 0; i < 4; ++i) {
    int gid = i * 512 + tid;
    int krow = gid >> 5, ksl = gid & 31;
    kst[i] = *(const half8*)(kg + ((size_t)(b * NSEQ + krow)) * CDIM + ksl * 8);
    int vd = gid >> 3, vsl = gid & 7;
    vst[i] = *(const half8*)(vtg + ((size_t)(b * CDIM + vd)) * NSEQ + vsl * 8);
  }
  #pragma unroll
  for (int i = 0; i < 4; ++i) {
    int gid = i * 512 + tid;
    int krow = gid >> 5, ksl = gid & 31;
    *(half8*)(smem + krow * 512 + ((ksl ^ (krow & 7)) << 4)) = kst[i];
    int vd = gid >> 3, vsl = gid & 7;
    *(half8*)(smem + 65536 + vd * 128 + ((vsl ^ (vd & 7)) << 4)) = vst[i];
  }
  __syncthreads();

  for (int t = 0; t < 64; ++t) {
    const int cur = t & 1;
    char* kb = smem + cur * 32768;
    char* vb = smem + 65536 + cur * 32768;

    // issue next tile's global loads early (T14: latency hides under compute)
    if (t < 63) {
      const int kv0 = (t + 1) * 64;
      #pragma unroll
      for (int i = 0; i < 4; ++i) {
        int gid = i * 512 + tid;
        int krow = gid >> 5, ksl = gid & 31;
        kst[i] = *(const half8*)(kg + ((size_t)(b * NSEQ + kv0 + krow)) * CDIM + ksl * 8);
        int vd = gid >> 3, vsl = gid & 7;
        vst[i] = *(const half8*)(vtg + ((size_t)(b * CDIM + vd)) * NSEQ + kv0 + vsl * 8);
      }
    }

    // ---- S = Q K^T : 32q x 32kv per wave, K-fragment reused across 2 A-tiles
    f32x4 sacc[2][2];
    #pragma unroll
    for (int mi = 0; mi < 2; ++mi)
      #pragma unroll
      for (int nc = 0; nc < 2; ++nc) sacc[mi][nc] = (f32x4){0,0,0,0};
    #pragma unroll
    for (int kc = 0; kc < 8; ++kc) {
      #pragma unroll
      for (int nc = 0; nc < 2; ++nc) {
        half8 kf = *(const half8*)(kb + (kvh * 32 + nc * 16 + lr) * 512 +
                                   (((kc * 4 + g) ^ (lr & 7)) << 4));
        #pragma unroll
        for (int mi = 0; mi < 2; ++mi)
          sacc[mi][nc] =
              __builtin_amdgcn_mfma_f32_16x16x32_f16(qf[mi][kc], kf, sacc[mi][nc], 0, 0, 0);
      }
    }

    // ---- partial row-max over this wave's 32 kv
    f32x4 pm[2];
    #pragma unroll
    for (int mi = 0; mi < 2; ++mi) pm[mi] = vmax4(sacc[mi][0], sacc[mi][1]);
    #pragma unroll
    for (int m = 1; m < 16; m <<= 1) {
      pm[0] = vmax4(pm[0], shfl_xor4(pm[0], m));
      pm[1] = vmax4(pm[1], shfl_xor4(pm[1], m));
    }
    if (lr == 0) {
      #pragma unroll
      for (int mi = 0; mi < 2; ++mi)
        #pragma unroll
        for (int r = 0; r < 4; ++r)
          pmaxb[kvh * 128 + qq * 32 + mi * 16 + g * 4 + r] = pm[mi][r];
    }
    __syncthreads();  // B1: partial maxes visible

    f32x4 mnew[2], al[2];
    #pragma unroll
    for (int mi = 0; mi < 2; ++mi) {
      f32x4 p0 = *(const f32x4*)(pmaxb + qq * 32 + mi * 16 + g * 4);
      f32x4 p1 = *(const f32x4*)(pmaxb + 128 + qq * 32 + mi * 16 + g * 4);
      mnew[mi] = vmax4(mrow[mi], vmax4(p0, p1));
      #pragma unroll
      for (int r = 0; r < 4; ++r) al[mi][r] = exp2f(mrow[mi][r] - mnew[mi][r]);
      mrow[mi] = mnew[mi];
    }
    if (kvh == 0 && lr == 0) {
      #pragma unroll
      for (int mi = 0; mi < 2; ++mi)
        #pragma unroll
        for (int r = 0; r < 4; ++r)
          alf[qq * 32 + mi * 16 + g * 4 + r] = al[mi][r];
    }

    // ---- P = exp2(S - m), write to pbuf (conflict-free swizzle), partial sums
    f32x4 rs[2] = {{0,0,0,0},{0,0,0,0}};
    #pragma unroll
    for (int mi = 0; mi < 2; ++mi) {
      #pragma unroll
      for (int nc = 0; nc < 2; ++nc) {
        f32x4 p;
        #pragma unroll
        for (int r = 0; r < 4; ++r) p[r] = exp2f(sacc[mi][nc][r] - mnew[mi][r]);
        rs[mi] += p;
        #pragma unroll
        for (int r = 0; r < 4; ++r) {
          int row  = qq * 32 + mi * 16 + g * 4 + r;
          int slot = (kvh * 4 + nc * 2 + (lr >> 3)) ^ ((g * 2 + (r >> 1)) & 7);
          *(_Float16*)(pbuf + row * 128 + slot * 16 + ((lr & 7) << 1)) = (_Float16)p[r];
        }
      }
    }
    #pragma unroll
    for (int m = 1; m < 16; m <<= 1) {
      rs[0] += shfl_xor4(rs[0], m);
      rs[1] += shfl_xor4(rs[1], m);
    }
    if (lr == 0) {
      #pragma unroll
      for (int mi = 0; mi < 2; ++mi)
        #pragma unroll
        for (int r = 0; r < 4; ++r)
          psumb[kvh * 128 + qq * 32 + mi * 16 + g * 4 + r] = rs[mi][r];
    }
    __syncthreads();  // B2: P + alf + partial sums visible

    #pragma unroll
    for (int mi = 0; mi < 2; ++mi) {
      f32x4 s0 = *(const f32x4*)(psumb + qq * 32 + mi * 16 + g * 4);
      f32x4 s1 = *(const f32x4*)(psumb + 128 + qq * 32 + mi * 16 + g * 4);
      lrow[mi] = lrow[mi] * al[mi] + (s0 + s1);
    }

    // ---- PV: rescale O by alpha, accumulate P[64q] x V[64d]
    #pragma unroll
    for (int mi = 0; mi < 4; ++mi) {
      f32x4 av = *(const f32x4*)(alf + qh * 64 + mi * 16 + g * 4);
      #pragma unroll
      for (int dc = 0; dc < 4; ++dc) o[mi][dc] *= av;
    }
    #pragma unroll
    for (int kc2 = 0; kc2 < 2; ++kc2) {
      half8 pf[4];
      #pragma unroll
      for (int mi = 0; mi < 4; ++mi)
        pf[mi] = *(const half8*)(pbuf + (qh * 64 + mi * 16 + lr) * 128 +
                                 (((kc2 * 4 + g) ^ ((lr >> 1) & 7)) << 4));
      #pragma unroll
      for (int dc = 0; dc < 4; ++dc) {
        half8 vf = *(const half8*)(vb + (dq * 64 + dc * 16 + lr) * 128 +
                                   (((kc2 * 4 + g) ^ (lr & 7)) << 4));
        #pragma unroll
        for (int mi = 0; mi < 4; ++mi)
          o[mi][dc] = __builtin_amdgcn_mfma_f32_16x16x32_f16(pf[mi], vf, o[mi][dc], 0, 0, 0);
      }
    }

    // ---- write next tile into the other K/V buffer (vmcnt waits land here)
    if (t < 63) {
      char* kn = smem + (cur ^ 1) * 32768;
      char* vn = smem + 65536 + (cur ^ 1) * 32768;
      #pragma unroll
      for (int i = 0; i < 4; ++i) {
        int gid = i * 512 + tid;
        int krow = gid >> 5, ksl = gid & 31;
        *(half8*)(kn + krow * 512 + ((ksl ^ (krow & 7)) << 4)) = kst[i];
        int vd = gid >> 3, vsl = gid & 7;
        *(half8*)(vn + vd * 128 + ((vsl ^ (vd & 7)) << 4)) = vst[i];
      }
    }
    __syncthreads();  // B3: staged writes visible / P-region safe for next iter
  }

  // ---- finalize: publish 1/l, normalize, stage O in LDS, coalesced store
  if (kvh == 0 && lr == 0) {
    #pragma unroll
    for (int mi = 0; mi < 2; ++mi)
      #pragma unroll
      for (int r = 0; r < 4; ++r)
        alf[qq * 32 + mi * 16 + g * 4 + r] = 1.0f / lrow[mi][r];
  }
  __syncthreads();
  _Float16* oL = (_Float16*)smem;  // [128][256] f16 = 64KB over K buffers
  #pragma unroll
  for (int mi = 0; mi < 4; ++mi) {
    f32x4 lv = *(const f32x4*)(alf + qh * 64 + mi * 16 + g * 4);
    #pragma unroll
    for (int dc = 0; dc < 4; ++dc) {
      #pragma unroll
      for (int r = 0; r < 4; ++r)
        oL[(qh * 64 + mi * 16 + g * 4 + r) * 256 + dq * 64 + dc * 16 + lr] =
            (_Float16)(o[mi][dc][r] * lv[r]);
    }
  }
  __syncthreads();
  #pragma unroll
  for (int i = 0; i < 8; ++i) {
    int p = i * 512 + tid;
    int row = p >> 5, sl = p & 31;   // 128 rows x 32 slots x 8 halves (R2 bug fixed)
    *(half8*)(og + ((size_t)(b * NSEQ + n0 + row)) * CDIM + sl * 8) =
        *(const half8*)(oL + row * 256 + sl * 8);
  }
}

// ---------------- launcher
extern "C" void kernel_launch(void* const* d_in, const int* in_sizes, int n_in,
                              void* d_out, int out_size, void* d_ws, size_t ws_size,
                              hipStream_t stream) {
  const float* x   = (const float*)d_in[0];
  const float* gam = (const float*)d_in[1];
  const float* bet = (const float*)d_in[2];
  const float* wq  = (const float*)d_in[3];
  const float* bq  = (const float*)d_in[4];
  const float* wk  = (const float*)d_in[5];
  const float* bk  = (const float*)d_in[6];
  const float* wv  = (const float*)d_in[7];
  const float* bv  = (const float*)d_in[8];
  const float* wp  = (const float*)d_in[9];
  const float* bp  = (const float*)d_in[10];
  float* out = (float*)d_out;

  char* ws = (char*)d_ws;
  float*    xnf = (float*)ws;                             // 32MB fp32 xn (residual)
  _Float16* xnh = (_Float16*)(ws + (32u << 20));          // 16MB f16 xn
  _Float16* qh  = (_Float16*)(ws + (48u << 20));          // 16MB q (scaled)
  _Float16* kh  = (_Float16*)(ws + (64u << 20));          // 16MB k
  _Float16* vth = (_Float16*)(ws + (80u << 20));          // 16MB v^T [b][c][n]
  _Float16* oh  = (_Float16*)(ws + (96u << 20));          // 16MB attn out

  (void)hipFuncSetAttribute((const void*)proj_kernel,
                            hipFuncAttributeMaxDynamicSharedMemorySize, 65536);
  (void)hipFuncSetAttribute((const void*)attn_kernel,
                            hipFuncAttributeMaxDynamicSharedMemorySize, ATTN_LDS);

  ln_kernel<<<NTOK / 4, 256, 0, stream>>>(x, gam, bet, xnf, xnh);
  proj_kernel<<<dim3(64, 4, 3), 256, 65536, stream>>>(
      xnh, wq, bq, wk, bk, wv, bv, wp, bp, qh, kh, vth, xnf, out, 0);
  attn_kernel<<<256, 512, ATTN_LDS, stream>>>(qh, kh, vth, oh);
  proj_kernel<<<dim3(64, 4, 1), 256, 65536, stream>>>(
      oh, wq, bq, wk, bk, wv, bv, wp, bp, qh, kh, vth, xnf, out, 3);
}

// Round 4
// 464.898 us; speedup vs baseline: 1.0016x; 1.0016x over previous
//
#include <hip/hip_runtime.h>
#include <cstdint>

#define NB    8
#define NSEQ  4096
#define CDIM  256
#define NTOK  (NB*NSEQ)

typedef _Float16 half8  __attribute__((ext_vector_type(8)));
typedef _Float16 half4v __attribute__((ext_vector_type(4)));
typedef float    f32x4  __attribute__((ext_vector_type(4)));

typedef unsigned int u32_g __attribute__((address_space(1)));
typedef unsigned int u32_l __attribute__((address_space(3)));

// direct global->LDS, 16B per lane (used by proj kernel only)
__device__ __forceinline__ void gload_lds16(const void* g, void* l) {
  __builtin_amdgcn_global_load_lds((u32_g*)(uintptr_t)g,
                                   (u32_l*)(uint32_t)(uintptr_t)l, 16, 0, 0);
}

__device__ __forceinline__ f32x4 vmax4(f32x4 a, f32x4 b) {
  f32x4 r;
  r[0] = fmaxf(a[0], b[0]); r[1] = fmaxf(a[1], b[1]);
  r[2] = fmaxf(a[2], b[2]); r[3] = fmaxf(a[3], b[3]);
  return r;
}

__device__ __forceinline__ f32x4 shfl_xor4(f32x4 v, int m) {
  f32x4 r;
  r[0] = __shfl_xor(v[0], m, 64); r[1] = __shfl_xor(v[1], m, 64);
  r[2] = __shfl_xor(v[2], m, 64); r[3] = __shfl_xor(v[3], m, 64);
  return r;
}

// ---------------- LayerNorm: one wave per token (C=256 = 64 lanes x float4)
__global__ __launch_bounds__(256) void ln_kernel(
    const float* __restrict__ x, const float* __restrict__ gam,
    const float* __restrict__ bet, float* __restrict__ xnf,
    _Float16* __restrict__ xnh) {
  const int lane = threadIdx.x & 63;
  const size_t tok = (size_t)blockIdx.x * 4 + (threadIdx.x >> 6);
  const float4 v = ((const float4*)(x + tok * CDIM))[lane];
  float s  = v.x + v.y + v.z + v.w;
  float s2 = v.x*v.x + v.y*v.y + v.z*v.z + v.w*v.w;
  #pragma unroll
  for (int m = 1; m < 64; m <<= 1) {
    s  += __shfl_xor(s,  m, 64);
    s2 += __shfl_xor(s2, m, 64);
  }
  const float mean = s * (1.0f / CDIM);
  const float rstd = rsqrtf(s2 * (1.0f / CDIM) - mean * mean + 1e-3f);
  const float4 gv = ((const float4*)gam)[lane];
  const float4 bv = ((const float4*)bet)[lane];
  float4 o;
  o.x = (v.x - mean) * rstd * gv.x + bv.x;
  o.y = (v.y - mean) * rstd * gv.y + bv.y;
  o.z = (v.z - mean) * rstd * gv.z + bv.z;
  o.w = (v.w - mean) * rstd * gv.w + bv.w;
  ((float4*)(xnf + tok * CDIM))[lane] = o;
  half4v h;
  h[0] = (_Float16)o.x; h[1] = (_Float16)o.y;
  h[2] = (_Float16)o.z; h[3] = (_Float16)o.w;
  ((half4v*)(xnh + tok * CDIM))[lane] = h;
}

// ---------------- projection GEMM (unchanged from R1)
__global__ __launch_bounds__(256, 2) void proj_kernel(
    const _Float16* __restrict__ inh,
    const float* __restrict__ wq_, const float* __restrict__ bq_,
    const float* __restrict__ wk_, const float* __restrict__ bk_,
    const float* __restrict__ wv_, const float* __restrict__ bv_,
    const float* __restrict__ wp_, const float* __restrict__ bp_,
    _Float16* __restrict__ qg, _Float16* __restrict__ kg, _Float16* __restrict__ vtg,
    const float* __restrict__ xnf, float* __restrict__ outf,
    int mode_base) {
  extern __shared__ char smem[];
  const int mode = mode_base + blockIdx.z;
  const float* wsel = (mode == 0) ? wq_ : (mode == 1) ? wk_ : (mode == 2) ? wv_ : wp_;
  const float* bsel = (mode == 0) ? bq_ : (mode == 1) ? bk_ : (mode == 2) ? bv_ : bp_;

  const int tid = threadIdx.x;
  const int lane = tid & 63;
  const int wid  = tid >> 6;     // 0..3
  const int g    = lane >> 4;    // 0..3
  const int lr   = lane & 15;
  const int jstrip = blockIdx.y; // 0..3
  const size_t tok0 = (size_t)blockIdx.x * 512;

  char* wt   = smem;             // [64 j][256 c] f16, XOR-swizzled (32KB)
  char* tile = smem + 32768;     // [64 tok][256 c] f16, swizzled (32KB)

  for (int i = 0; i < 64; ++i) {
    int idx = i * 256 + tid;
    int c = idx >> 6, j = idx & 63;
    float val = wsel[(size_t)c * CDIM + jstrip * 64 + j];
    *(_Float16*)(wt + j * 512 + ((((c >> 3) ^ (j & 7))) << 4) + ((c & 7) << 1)) =
        (_Float16)val;
  }
  float bjv[4];
  #pragma unroll
  for (int jc = 0; jc < 4; ++jc) bjv[jc] = bsel[jstrip * 64 + jc * 16 + lr];
  __syncthreads();

  for (int t = 0; t < 8; ++t) {
    const size_t trow0 = tok0 + t * 64;
    #pragma unroll
    for (int i = 0; i < 8; ++i) {
      int pbase = (i * 4 + wid) * 64;
      int p = pbase + lane;
      int row = p >> 5, sl = p & 31;
      gload_lds16(inh + (trow0 + row) * CDIM + (size_t)((sl ^ (row & 7)) * 8),
                  tile + pbase * 16);
    }
    __syncthreads();

    f32x4 acc[4] = {{0,0,0,0},{0,0,0,0},{0,0,0,0},{0,0,0,0}};
    #pragma unroll
    for (int kc = 0; kc < 8; ++kc) {
      half8 a = *(const half8*)(tile + (wid * 16 + lr) * 512 +
                                ((((kc << 2) | g) ^ (lr & 7)) << 4));
      #pragma unroll
      for (int jc = 0; jc < 4; ++jc) {
        half8 bf = *(const half8*)(wt + (jc * 16 + lr) * 512 +
                                   ((((kc << 2) | g) ^ (lr & 7)) << 4));
        acc[jc] = __builtin_amdgcn_mfma_f32_16x16x32_f16(a, bf, acc[jc], 0, 0, 0);
      }
    }

    if (mode == 3) {
      #pragma unroll
      for (int jc = 0; jc < 4; ++jc) {
        #pragma unroll
        for (int r = 0; r < 4; ++r) {
          size_t row = trow0 + wid * 16 + g * 4 + r;
          size_t off = row * CDIM + jstrip * 64 + jc * 16 + lr;
          outf[off] = acc[jc][r] + bjv[jc] + xnf[off];
        }
      }
    } else {
      const float csc = (mode == 0) ? 0.09016844005556021f : 1.0f; // log2(e)/16
      __syncthreads();
      _Float16* ot = (_Float16*)tile;  // [64][72]
      #pragma unroll
      for (int jc = 0; jc < 4; ++jc)
        #pragma unroll
        for (int r = 0; r < 4; ++r)
          ot[(wid * 16 + g * 4 + r) * 72 + jc * 16 + lr] =
              (_Float16)((acc[jc][r] + bjv[jc]) * csc);
      __syncthreads();
      if (mode != 2) {
        _Float16* dst = (mode == 0) ? qg : kg;
        #pragma unroll
        for (int it = 0; it < 2; ++it) {
          int s = it * 256 + tid;
          int row = s >> 3, sl = s & 7;
          half8 vv = *(const half8*)(ot + row * 72 + sl * 8);
          *(half8*)(dst + (trow0 + row) * CDIM + jstrip * 64 + sl * 8) = vv;
        }
      } else {
        #pragma unroll
        for (int it = 0; it < 2; ++it) {
          int s = it * 256 + tid;
          int j = s >> 3, ns = s & 7;
          half8 vv;
          #pragma unroll
          for (int e = 0; e < 8; ++e) vv[e] = ot[(ns * 8 + e) * 72 + j];
          size_t bb  = trow0 >> 12;
          size_t nin = (trow0 & 4095) + ns * 8;
          *(half8*)(vtg + ((size_t)bb * CDIM + jstrip * 64 + j) * NSEQ + nin) = vv;
        }
      }
    }
    __syncthreads();
  }
}

// ---------------- flash attention v2: QBLK=128, KVBLK=64, 8 waves
// LDS: K dbuf 2x32KB @0, V dbuf 2x32KB @65536, P 16KB @131072,
//      pmax 1KB @147456, psum 1KB @148480, alf 512B @149504
#define ATTN_LDS 150016

// NOTE: launch_bounds(512, 1): LDS (150KB) limits to 1 block/CU regardless;
// the "2" in R3 capped VGPRs at 128 and forced ~17MB/dispatch of scratch
// spill (WRITE_SIZE 16->33.8MB). With 256-VGPR budget the ~220-reg live set
// (qf 64 + o 64 + kst/vst 32 + sacc/temps) fits with zero spill.
__global__ __launch_bounds__(512, 1) void attn_kernel(
    const _Float16* __restrict__ qg, const _Float16* __restrict__ kg,
    const _Float16* __restrict__ vtg, _Float16* __restrict__ og) {
  extern __shared__ char smem[];
  char*  pbuf  = smem + 131072;           // [128 q][8 slot][8 f16], swizzle f(row)=(row>>1)&7
  float* pmaxb = (float*)(smem + 147456); // [2 kvh][128 rows]
  float* psumb = (float*)(smem + 148480); // [2 kvh][128 rows]
  float* alf   = (float*)(smem + 149504); // [128]

  const int tid  = threadIdx.x;
  const int lane = tid & 63;
  const int wid  = tid >> 6;     // 0..7
  const int g    = lane >> 4;
  const int lr   = lane & 15;
  const int b    = blockIdx.x & 7;       // XCD-affine: batch pinned to one XCD's L2
  const int n0   = (blockIdx.x >> 3) * 128;
  // S roles: wave = 32q x 32kv
  const int qq   = wid >> 1;     // 0..3 (q 32-row group)
  const int kvh  = wid & 1;      // kv half
  // PV roles: wave = 64q x 64d
  const int qh   = wid & 1;
  const int dq   = wid >> 1;

  // Q fragments: 2 A-tiles x 8 kc (64 VGPR), scale*log2e pre-folded
  half8 qf[2][8];
  #pragma unroll
  for (int mi = 0; mi < 2; ++mi) {
    const _Float16* qp =
        qg + ((size_t)(b * NSEQ + n0 + qq * 32 + mi * 16 + lr)) * CDIM + g * 8;
    #pragma unroll
    for (int kc = 0; kc < 8; ++kc) qf[mi][kc] = *(const half8*)(qp + kc * 32);
  }

  f32x4 o[4][4];  // [mi2][dc]: rows qh*64+mi2*16+4g+r, cols dq*64+dc*16+lr
  #pragma unroll
  for (int mi = 0; mi < 4; ++mi)
    #pragma unroll
    for (int dc = 0; dc < 4; ++dc) o[mi][dc] = (f32x4){0,0,0,0};
  f32x4 mrow[2], lrow[2];
  #pragma unroll
  for (int mi = 0; mi < 2; ++mi) {
    mrow[mi] = (f32x4){-1e30f,-1e30f,-1e30f,-1e30f};
    lrow[mi] = (f32x4){0,0,0,0};
  }

  half8 kst[4], vst[4];
  // prologue: stage tile 0 into buffer 0
  #pragma unroll
  for (int i = 0; i < 4; ++i) {
    int gid = i * 512 + tid;
    int krow = gid >> 5, ksl = gid & 31;
    kst[i] = *(const half8*)(kg + ((size_t)(b * NSEQ + krow)) * CDIM + ksl * 8);
    int vd = gid >> 3, vsl = gid & 7;
    vst[i] = *(const half8*)(vtg + ((size_t)(b * CDIM + vd)) * NSEQ + vsl * 8);
  }
  #pragma unroll
  for (int i = 0; i < 4; ++i) {
    int gid = i * 512 + tid;
    int krow = gid >> 5, ksl = gid & 31;
    *(half8*)(smem + krow * 512 + ((ksl ^ (krow & 7)) << 4)) = kst[i];
    int vd = gid >> 3, vsl = gid & 7;
    *(half8*)(smem + 65536 + vd * 128 + ((vsl ^ (vd & 7)) << 4)) = vst[i];
  }
  __syncthreads();

  for (int t = 0; t < 64; ++t) {
    const int cur = t & 1;
    char* kb = smem + cur * 32768;
    char* vb = smem + 65536 + cur * 32768;

    // issue next tile's global loads early (T14: latency hides under compute)
    if (t < 63) {
      const int kv0 = (t + 1) * 64;
      #pragma unroll
      for (int i = 0; i < 4; ++i) {
        int gid = i * 512 + tid;
        int krow = gid >> 5, ksl = gid & 31;
        kst[i] = *(const half8*)(kg + ((size_t)(b * NSEQ + kv0 + krow)) * CDIM + ksl * 8);
        int vd = gid >> 3, vsl = gid & 7;
        vst[i] = *(const half8*)(vtg + ((size_t)(b * CDIM + vd)) * NSEQ + kv0 + vsl * 8);
      }
    }

    // ---- S = Q K^T : 32q x 32kv per wave, K-fragment reused across 2 A-tiles
    f32x4 sacc[2][2];
    #pragma unroll
    for (int mi = 0; mi < 2; ++mi)
      #pragma unroll
      for (int nc = 0; nc < 2; ++nc) sacc[mi][nc] = (f32x4){0,0,0,0};
    #pragma unroll
    for (int kc = 0; kc < 8; ++kc) {
      #pragma unroll
      for (int nc = 0; nc < 2; ++nc) {
        half8 kf = *(const half8*)(kb + (kvh * 32 + nc * 16 + lr) * 512 +
                                   (((kc * 4 + g) ^ (lr & 7)) << 4));
        #pragma unroll
        for (int mi = 0; mi < 2; ++mi)
          sacc[mi][nc] =
              __builtin_amdgcn_mfma_f32_16x16x32_f16(qf[mi][kc], kf, sacc[mi][nc], 0, 0, 0);
      }
    }

    // ---- partial row-max over this wave's 32 kv
    f32x4 pm[2];
    #pragma unroll
    for (int mi = 0; mi < 2; ++mi) pm[mi] = vmax4(sacc[mi][0], sacc[mi][1]);
    #pragma unroll
    for (int m = 1; m < 16; m <<= 1) {
      pm[0] = vmax4(pm[0], shfl_xor4(pm[0], m));
      pm[1] = vmax4(pm[1], shfl_xor4(pm[1], m));
    }
    if (lr == 0) {
      #pragma unroll
      for (int mi = 0; mi < 2; ++mi)
        #pragma unroll
        for (int r = 0; r < 4; ++r)
          pmaxb[kvh * 128 + qq * 32 + mi * 16 + g * 4 + r] = pm[mi][r];
    }
    __syncthreads();  // B1: partial maxes visible

    f32x4 mnew[2], al[2];
    #pragma unroll
    for (int mi = 0; mi < 2; ++mi) {
      f32x4 p0 = *(const f32x4*)(pmaxb + qq * 32 + mi * 16 + g * 4);
      f32x4 p1 = *(const f32x4*)(pmaxb + 128 + qq * 32 + mi * 16 + g * 4);
      mnew[mi] = vmax4(mrow[mi], vmax4(p0, p1));
      #pragma unroll
      for (int r = 0; r < 4; ++r) al[mi][r] = exp2f(mrow[mi][r] - mnew[mi][r]);
      mrow[mi] = mnew[mi];
    }
    if (kvh == 0 && lr == 0) {
      #pragma unroll
      for (int mi = 0; mi < 2; ++mi)
        #pragma unroll
        for (int r = 0; r < 4; ++r)
          alf[qq * 32 + mi * 16 + g * 4 + r] = al[mi][r];
    }

    // ---- P = exp2(S - m), write to pbuf (conflict-free swizzle), partial sums
    f32x4 rs[2] = {{0,0,0,0},{0,0,0,0}};
    #pragma unroll
    for (int mi = 0; mi < 2; ++mi) {
      #pragma unroll
      for (int nc = 0; nc < 2; ++nc) {
        f32x4 p;
        #pragma unroll
        for (int r = 0; r < 4; ++r) p[r] = exp2f(sacc[mi][nc][r] - mnew[mi][r]);
        rs[mi] += p;
        #pragma unroll
        for (int r = 0; r < 4; ++r) {
          int row  = qq * 32 + mi * 16 + g * 4 + r;
          int slot = (kvh * 4 + nc * 2 + (lr >> 3)) ^ ((g * 2 + (r >> 1)) & 7);
          *(_Float16*)(pbuf + row * 128 + slot * 16 + ((lr & 7) << 1)) = (_Float16)p[r];
        }
      }
    }
    #pragma unroll
    for (int m = 1; m < 16; m <<= 1) {
      rs[0] += shfl_xor4(rs[0], m);
      rs[1] += shfl_xor4(rs[1], m);
    }
    if (lr == 0) {
      #pragma unroll
      for (int mi = 0; mi < 2; ++mi)
        #pragma unroll
        for (int r = 0; r < 4; ++r)
          psumb[kvh * 128 + qq * 32 + mi * 16 + g * 4 + r] = rs[mi][r];
    }
    __syncthreads();  // B2: P + alf + partial sums visible

    #pragma unroll
    for (int mi = 0; mi < 2; ++mi) {
      f32x4 s0 = *(const f32x4*)(psumb + qq * 32 + mi * 16 + g * 4);
      f32x4 s1 = *(const f32x4*)(psumb + 128 + qq * 32 + mi * 16 + g * 4);
      lrow[mi] = lrow[mi] * al[mi] + (s0 + s1);
    }

    // ---- PV: rescale O by alpha, accumulate P[64q] x V[64d]
    #pragma unroll
    for (int mi = 0; mi < 4; ++mi) {
      f32x4 av = *(const f32x4*)(alf + qh * 64 + mi * 16 + g * 4);
      #pragma unroll
      for (int dc = 0; dc < 4; ++dc) o[mi][dc] *= av;
    }
    #pragma unroll
    for (int kc2 = 0; kc2 < 2; ++kc2) {
      half8 pf[4];
      #pragma unroll
      for (int mi = 0; mi < 4; ++mi)
        pf[mi] = *(const half8*)(pbuf + (qh * 64 + mi * 16 + lr) * 128 +
                                 (((kc2 * 4 + g) ^ ((lr >> 1) & 7)) << 4));
      #pragma unroll
      for (int dc = 0; dc < 4; ++dc) {
        half8 vf = *(const half8*)(vb + (dq * 64 + dc * 16 + lr) * 128 +
                                   (((kc2 * 4 + g) ^ (lr & 7)) << 4));
        #pragma unroll
        for (int mi = 0; mi < 4; ++mi)
          o[mi][dc] = __builtin_amdgcn_mfma_f32_16x16x32_f16(pf[mi], vf, o[mi][dc], 0, 0, 0);
      }
    }

    // ---- write next tile into the other K/V buffer (vmcnt waits land here)
    if (t < 63) {
      char* kn = smem + (cur ^ 1) * 32768;
      char* vn = smem + 65536 + (cur ^ 1) * 32768;
      #pragma unroll
      for (int i = 0; i < 4; ++i) {
        int gid = i * 512 + tid;
        int krow = gid >> 5, ksl = gid & 31;
        *(half8*)(kn + krow * 512 + ((ksl ^ (krow & 7)) << 4)) = kst[i];
        int vd = gid >> 3, vsl = gid & 7;
        *(half8*)(vn + vd * 128 + ((vsl ^ (vd & 7)) << 4)) = vst[i];
      }
    }
    __syncthreads();  // B3: staged writes visible / P-region safe for next iter
  }

  // ---- finalize: publish 1/l, normalize, stage O in LDS, coalesced store
  if (kvh == 0 && lr == 0) {
    #pragma unroll
    for (int mi = 0; mi < 2; ++mi)
      #pragma unroll
      for (int r = 0; r < 4; ++r)
        alf[qq * 32 + mi * 16 + g * 4 + r] = 1.0f / lrow[mi][r];
  }
  __syncthreads();
  _Float16* oL = (_Float16*)smem;  // [128][256] f16 = 64KB over K buffers
  #pragma unroll
  for (int mi = 0; mi < 4; ++mi) {
    f32x4 lv = *(const f32x4*)(alf + qh * 64 + mi * 16 + g * 4);
    #pragma unroll
    for (int dc = 0; dc < 4; ++dc) {
      #pragma unroll
      for (int r = 0; r < 4; ++r)
        oL[(qh * 64 + mi * 16 + g * 4 + r) * 256 + dq * 64 + dc * 16 + lr] =
            (_Float16)(o[mi][dc][r] * lv[r]);
    }
  }
  __syncthreads();
  #pragma unroll
  for (int i = 0; i < 8; ++i) {
    int p = i * 512 + tid;
    int row = p >> 5, sl = p & 31;   // 128 rows x 32 slots x 8 halves
    *(half8*)(og + ((size_t)(b * NSEQ + n0 + row)) * CDIM + sl * 8) =
        *(const half8*)(oL + row * 256 + sl * 8);
  }
}

// ---------------- launcher
extern "C" void kernel_launch(void* const* d_in, const int* in_sizes, int n_in,
                              void* d_out, int out_size, void* d_ws, size_t ws_size,
                              hipStream_t stream) {
  const float* x   = (const float*)d_in[0];
  const float* gam = (const float*)d_in[1];
  const float* bet = (const float*)d_in[2];
  const float* wq  = (const float*)d_in[3];
  const float* bq  = (const float*)d_in[4];
  const float* wk  = (const float*)d_in[5];
  const float* bk  = (const float*)d_in[6];
  const float* wv  = (const float*)d_in[7];
  const float* bv  = (const float*)d_in[8];
  const float* wp  = (const float*)d_in[9];
  const float* bp  = (const float*)d_in[10];
  float* out = (float*)d_out;

  char* ws = (char*)d_ws;
  float*    xnf = (float*)ws;                             // 32MB fp32 xn (residual)
  _Float16* xnh = (_Float16*)(ws + (32u << 20));          // 16MB f16 xn
  _Float16* qh  = (_Float16*)(ws + (48u << 20));          // 16MB q (scaled)
  _Float16* kh  = (_Float16*)(ws + (64u << 20));          // 16MB k
  _Float16* vth = (_Float16*)(ws + (80u << 20));          // 16MB v^T [b][c][n]
  _Float16* oh  = (_Float16*)(ws + (96u << 20));          // 16MB attn out

  (void)hipFuncSetAttribute((const void*)proj_kernel,
                            hipFuncAttributeMaxDynamicSharedMemorySize, 65536);
  (void)hipFuncSetAttribute((const void*)attn_kernel,
                            hipFuncAttributeMaxDynamicSharedMemorySize, ATTN_LDS);

  ln_kernel<<<NTOK / 4, 256, 0, stream>>>(x, gam, bet, xnf, xnh);
  proj_kernel<<<dim3(64, 4, 3), 256, 65536, stream>>>(
      xnh, wq, bq, wk, bk, wv, bv, wp, bp, qh, kh, vth, xnf, out, 0);
  attn_kernel<<<256, 512, ATTN_LDS, stream>>>(qh, kh, vth, oh);
  proj_kernel<<<dim3(64, 4, 1), 256, 65536, stream>>>(
      oh, wq, bq, wk, bk, wv, bv, wp, bp, qh, kh, vth, xnf, out, 3);
}

// Round 5
// 355.805 us; speedup vs baseline: 1.3087x; 1.3066x over previous
//
#include <hip/hip_runtime.h>
#include <cstdint>

#define NB    8
#define NSEQ  4096
#define CDIM  256
#define NTOK  (NB*NSEQ)

typedef _Float16 half8  __attribute__((ext_vector_type(8)));
typedef _Float16 half4v __attribute__((ext_vector_type(4)));
typedef float    f32x4  __attribute__((ext_vector_type(4)));

typedef unsigned int u32_g __attribute__((address_space(1)));
typedef unsigned int u32_l __attribute__((address_space(3)));

// direct global->LDS, 16B per lane; LDS dest = wave-uniform base + lane*16
__device__ __forceinline__ void gload_lds16(const void* g, void* l) {
  __builtin_amdgcn_global_load_lds((u32_g*)(uintptr_t)g,
                                   (u32_l*)(uint32_t)(uintptr_t)l, 16, 0, 0);
}

__device__ __forceinline__ f32x4 vmax4(f32x4 a, f32x4 b) {
  f32x4 r;
  r[0] = fmaxf(a[0], b[0]); r[1] = fmaxf(a[1], b[1]);
  r[2] = fmaxf(a[2], b[2]); r[3] = fmaxf(a[3], b[3]);
  return r;
}

__device__ __forceinline__ f32x4 shfl_xor4(f32x4 v, int m) {
  f32x4 r;
  r[0] = __shfl_xor(v[0], m, 64); r[1] = __shfl_xor(v[1], m, 64);
  r[2] = __shfl_xor(v[2], m, 64); r[3] = __shfl_xor(v[3], m, 64);
  return r;
}

// ---------------- LayerNorm: one wave per token (C=256 = 64 lanes x float4)
__global__ __launch_bounds__(256) void ln_kernel(
    const float* __restrict__ x, const float* __restrict__ gam,
    const float* __restrict__ bet, float* __restrict__ xnf,
    _Float16* __restrict__ xnh) {
  const int lane = threadIdx.x & 63;
  const size_t tok = (size_t)blockIdx.x * 4 + (threadIdx.x >> 6);
  const float4 v = ((const float4*)(x + tok * CDIM))[lane];
  float s  = v.x + v.y + v.z + v.w;
  float s2 = v.x*v.x + v.y*v.y + v.z*v.z + v.w*v.w;
  #pragma unroll
  for (int m = 1; m < 64; m <<= 1) {
    s  += __shfl_xor(s,  m, 64);
    s2 += __shfl_xor(s2, m, 64);
  }
  const float mean = s * (1.0f / CDIM);
  const float rstd = rsqrtf(s2 * (1.0f / CDIM) - mean * mean + 1e-3f);
  const float4 gv = ((const float4*)gam)[lane];
  const float4 bv = ((const float4*)bet)[lane];
  float4 o;
  o.x = (v.x - mean) * rstd * gv.x + bv.x;
  o.y = (v.y - mean) * rstd * gv.y + bv.y;
  o.z = (v.z - mean) * rstd * gv.z + bv.z;
  o.w = (v.w - mean) * rstd * gv.w + bv.w;
  ((float4*)(xnf + tok * CDIM))[lane] = o;
  half4v h;
  h[0] = (_Float16)o.x; h[1] = (_Float16)o.y;
  h[2] = (_Float16)o.z; h[3] = (_Float16)o.w;
  ((half4v*)(xnh + tok * CDIM))[lane] = h;
}

// ---------------- projection GEMM (unchanged from R1)
__global__ __launch_bounds__(256, 2) void proj_kernel(
    const _Float16* __restrict__ inh,
    const float* __restrict__ wq_, const float* __restrict__ bq_,
    const float* __restrict__ wk_, const float* __restrict__ bk_,
    const float* __restrict__ wv_, const float* __restrict__ bv_,
    const float* __restrict__ wp_, const float* __restrict__ bp_,
    _Float16* __restrict__ qg, _Float16* __restrict__ kg, _Float16* __restrict__ vtg,
    const float* __restrict__ xnf, float* __restrict__ outf,
    int mode_base) {
  extern __shared__ char smem[];
  const int mode = mode_base + blockIdx.z;
  const float* wsel = (mode == 0) ? wq_ : (mode == 1) ? wk_ : (mode == 2) ? wv_ : wp_;
  const float* bsel = (mode == 0) ? bq_ : (mode == 1) ? bk_ : (mode == 2) ? bv_ : bp_;

  const int tid = threadIdx.x;
  const int lane = tid & 63;
  const int wid  = tid >> 6;     // 0..3
  const int g    = lane >> 4;    // 0..3
  const int lr   = lane & 15;
  const int jstrip = blockIdx.y; // 0..3
  const size_t tok0 = (size_t)blockIdx.x * 512;

  char* wt   = smem;             // [64 j][256 c] f16, XOR-swizzled (32KB)
  char* tile = smem + 32768;     // [64 tok][256 c] f16, swizzled (32KB)

  for (int i = 0; i < 64; ++i) {
    int idx = i * 256 + tid;
    int c = idx >> 6, j = idx & 63;
    float val = wsel[(size_t)c * CDIM + jstrip * 64 + j];
    *(_Float16*)(wt + j * 512 + ((((c >> 3) ^ (j & 7))) << 4) + ((c & 7) << 1)) =
        (_Float16)val;
  }
  float bjv[4];
  #pragma unroll
  for (int jc = 0; jc < 4; ++jc) bjv[jc] = bsel[jstrip * 64 + jc * 16 + lr];
  __syncthreads();

  for (int t = 0; t < 8; ++t) {
    const size_t trow0 = tok0 + t * 64;
    #pragma unroll
    for (int i = 0; i < 8; ++i) {
      int pbase = (i * 4 + wid) * 64;
      int p = pbase + lane;
      int row = p >> 5, sl = p & 31;
      gload_lds16(inh + (trow0 + row) * CDIM + (size_t)((sl ^ (row & 7)) * 8),
                  tile + pbase * 16);
    }
    __syncthreads();

    f32x4 acc[4] = {{0,0,0,0},{0,0,0,0},{0,0,0,0},{0,0,0,0}};
    #pragma unroll
    for (int kc = 0; kc < 8; ++kc) {
      half8 a = *(const half8*)(tile + (wid * 16 + lr) * 512 +
                                ((((kc << 2) | g) ^ (lr & 7)) << 4));
      #pragma unroll
      for (int jc = 0; jc < 4; ++jc) {
        half8 bf = *(const half8*)(wt + (jc * 16 + lr) * 512 +
                                   ((((kc << 2) | g) ^ (lr & 7)) << 4));
        acc[jc] = __builtin_amdgcn_mfma_f32_16x16x32_f16(a, bf, acc[jc], 0, 0, 0);
      }
    }

    if (mode == 3) {
      #pragma unroll
      for (int jc = 0; jc < 4; ++jc) {
        #pragma unroll
        for (int r = 0; r < 4; ++r) {
          size_t row = trow0 + wid * 16 + g * 4 + r;
          size_t off = row * CDIM + jstrip * 64 + jc * 16 + lr;
          outf[off] = acc[jc][r] + bjv[jc] + xnf[off];
        }
      }
    } else {
      const float csc = (mode == 0) ? 0.09016844005556021f : 1.0f; // log2(e)/16
      __syncthreads();
      _Float16* ot = (_Float16*)tile;  // [64][72]
      #pragma unroll
      for (int jc = 0; jc < 4; ++jc)
        #pragma unroll
        for (int r = 0; r < 4; ++r)
          ot[(wid * 16 + g * 4 + r) * 72 + jc * 16 + lr] =
              (_Float16)((acc[jc][r] + bjv[jc]) * csc);
      __syncthreads();
      if (mode != 2) {
        _Float16* dst = (mode == 0) ? qg : kg;
        #pragma unroll
        for (int it = 0; it < 2; ++it) {
          int s = it * 256 + tid;
          int row = s >> 3, sl = s & 7;
          half8 vv = *(const half8*)(ot + row * 72 + sl * 8);
          *(half8*)(dst + (trow0 + row) * CDIM + jstrip * 64 + sl * 8) = vv;
        }
      } else {
        #pragma unroll
        for (int it = 0; it < 2; ++it) {
          int s = it * 256 + tid;
          int j = s >> 3, ns = s & 7;
          half8 vv;
          #pragma unroll
          for (int e = 0; e < 8; ++e) vv[e] = ot[(ns * 8 + e) * 72 + j];
          size_t bb  = trow0 >> 12;
          size_t nin = (trow0 & 4095) + ns * 8;
          *(half8*)(vtg + ((size_t)bb * CDIM + jstrip * 64 + j) * NSEQ + nin) = vv;
        }
      }
    }
    __syncthreads();
  }
}

// ---------------- flash attention v3: QBLK=128, KVBLK=64, 8 waves
// K/V staged via global_load_lds into DOUBLE-buffered LDS (issue t+1 at top of
// iter t; completes at B1's implicit vmcnt drain, hidden under S-phase).
// No reg-staging -> live set ~190 VGPR. amdgpu_waves_per_eu(2,2) sets the RA
// budget to 512/2 = 256 regs (LDS pins occupancy to 1 block/CU = 2 waves/EU
// anyway); R3/R4 showed launch_bounds' 2nd arg leaves the budget at 128 and
// forces ~17MB/dispatch scratch spill (WRITE_SIZE 16->33.8MB).
// LDS: K dbuf 2x32KB @0, V dbuf 2x32KB @65536, P 16KB @131072,
//      pmax 1KB @147456, psum 1KB @148480, alf 512B @149504
#define ATTN_LDS 150016

__global__ __launch_bounds__(512)
__attribute__((amdgpu_waves_per_eu(2, 2)))
void attn_kernel(
    const _Float16* __restrict__ qg, const _Float16* __restrict__ kg,
    const _Float16* __restrict__ vtg, _Float16* __restrict__ og) {
  extern __shared__ char smem[];
  char*  pbuf  = smem + 131072;           // [128 q][8 slot][8 f16], swizzled
  float* pmaxb = (float*)(smem + 147456); // [2 kvh][128 rows]
  float* psumb = (float*)(smem + 148480); // [2 kvh][128 rows]
  float* alf   = (float*)(smem + 149504); // [128]

  const int tid  = threadIdx.x;
  const int lane = tid & 63;
  const int wid  = tid >> 6;     // 0..7
  const int g    = lane >> 4;
  const int lr   = lane & 15;
  const int b    = blockIdx.x & 7;       // XCD-affine: batch pinned to one XCD's L2
  const int n0   = (blockIdx.x >> 3) * 128;
  // S roles: wave = 32q x 32kv
  const int qq   = wid >> 1;     // 0..3 (q 32-row group)
  const int kvh  = wid & 1;      // kv half
  // PV roles: wave = 64q x 64d
  const int qh   = wid & 1;
  const int dq   = wid >> 1;

  // Q fragments: 2 A-tiles x 8 kc (64 VGPR), scale*log2e pre-folded
  half8 qf[2][8];
  #pragma unroll
  for (int mi = 0; mi < 2; ++mi) {
    const _Float16* qp =
        qg + ((size_t)(b * NSEQ + n0 + qq * 32 + mi * 16 + lr)) * CDIM + g * 8;
    #pragma unroll
    for (int kc = 0; kc < 8; ++kc) qf[mi][kc] = *(const half8*)(qp + kc * 32);
  }

  f32x4 o[4][4];  // [mi2][dc]: rows qh*64+mi2*16+4g+r, cols dq*64+dc*16+lr
  #pragma unroll
  for (int mi = 0; mi < 4; ++mi)
    #pragma unroll
    for (int dc = 0; dc < 4; ++dc) o[mi][dc] = (f32x4){0,0,0,0};
  f32x4 mrow[2], lrow[2];
  #pragma unroll
  for (int mi = 0; mi < 2; ++mi) {
    mrow[mi] = (f32x4){-1e30f,-1e30f,-1e30f,-1e30f};
    lrow[mi] = (f32x4){0,0,0,0};
  }

  // prologue: stage tile 0 into buffer 0 (linear LDS dest + pre-swizzled src)
  #pragma unroll
  for (int i = 0; i < 4; ++i) {
    int pbase = (i * 8 + wid) * 64;
    int p = pbase + lane;
    int row = p >> 5, sl = p & 31;
    gload_lds16(kg + ((size_t)(b * NSEQ + row)) * CDIM + (sl ^ (row & 7)) * 8,
                smem + pbase * 16);
    int d = p >> 3, vsl = p & 7;
    gload_lds16(vtg + ((size_t)(b * CDIM + d)) * NSEQ + (vsl ^ (d & 7)) * 8,
                smem + 65536 + pbase * 16);
  }
  __syncthreads();

  for (int t = 0; t < 64; ++t) {
    const int cur = t & 1;
    char* kb = smem + cur * 32768;
    char* vb = smem + 65536 + cur * 32768;

    // issue next tile's global_load_lds into the other buffer (completes by B1)
    if (t < 63) {
      const int kv0n = (t + 1) * 64;
      char* kn = smem + (cur ^ 1) * 32768;
      char* vn = smem + 65536 + (cur ^ 1) * 32768;
      #pragma unroll
      for (int i = 0; i < 4; ++i) {
        int pbase = (i * 8 + wid) * 64;
        int p = pbase + lane;
        int row = p >> 5, sl = p & 31;
        gload_lds16(kg + ((size_t)(b * NSEQ + kv0n + row)) * CDIM + (sl ^ (row & 7)) * 8,
                    kn + pbase * 16);
        int d = p >> 3, vsl = p & 7;
        gload_lds16(vtg + ((size_t)(b * CDIM + d)) * NSEQ + kv0n + (vsl ^ (d & 7)) * 8,
                    vn + pbase * 16);
      }
    }

    // ---- S = Q K^T : 32q x 32kv per wave, K-fragment reused across 2 A-tiles
    f32x4 sacc[2][2];
    #pragma unroll
    for (int mi = 0; mi < 2; ++mi)
      #pragma unroll
      for (int nc = 0; nc < 2; ++nc) sacc[mi][nc] = (f32x4){0,0,0,0};
    #pragma unroll
    for (int kc = 0; kc < 8; ++kc) {
      #pragma unroll
      for (int nc = 0; nc < 2; ++nc) {
        half8 kf = *(const half8*)(kb + (kvh * 32 + nc * 16 + lr) * 512 +
                                   (((kc * 4 + g) ^ (lr & 7)) << 4));
        #pragma unroll
        for (int mi = 0; mi < 2; ++mi)
          sacc[mi][nc] =
              __builtin_amdgcn_mfma_f32_16x16x32_f16(qf[mi][kc], kf, sacc[mi][nc], 0, 0, 0);
      }
    }

    // ---- partial row-max over this wave's 32 kv
    f32x4 pm[2];
    #pragma unroll
    for (int mi = 0; mi < 2; ++mi) pm[mi] = vmax4(sacc[mi][0], sacc[mi][1]);
    #pragma unroll
    for (int m = 1; m < 16; m <<= 1) {
      pm[0] = vmax4(pm[0], shfl_xor4(pm[0], m));
      pm[1] = vmax4(pm[1], shfl_xor4(pm[1], m));
    }
    if (lr == 0) {
      #pragma unroll
      for (int mi = 0; mi < 2; ++mi)
        #pragma unroll
        for (int r = 0; r < 4; ++r)
          pmaxb[kvh * 128 + qq * 32 + mi * 16 + g * 4 + r] = pm[mi][r];
    }
    __syncthreads();  // B1: partial maxes visible (+ staging vmcnt drained)

    f32x4 mnew[2], al[2];
    #pragma unroll
    for (int mi = 0; mi < 2; ++mi) {
      f32x4 p0 = *(const f32x4*)(pmaxb + qq * 32 + mi * 16 + g * 4);
      f32x4 p1 = *(const f32x4*)(pmaxb + 128 + qq * 32 + mi * 16 + g * 4);
      mnew[mi] = vmax4(mrow[mi], vmax4(p0, p1));
      #pragma unroll
      for (int r = 0; r < 4; ++r) al[mi][r] = exp2f(mrow[mi][r] - mnew[mi][r]);
      mrow[mi] = mnew[mi];
    }
    if (kvh == 0 && lr == 0) {
      #pragma unroll
      for (int mi = 0; mi < 2; ++mi)
        #pragma unroll
        for (int r = 0; r < 4; ++r)
          alf[qq * 32 + mi * 16 + g * 4 + r] = al[mi][r];
    }

    // ---- P = exp2(S - m), write to pbuf (conflict-free swizzle), partial sums
    f32x4 rs[2] = {{0,0,0,0},{0,0,0,0}};
    #pragma unroll
    for (int mi = 0; mi < 2; ++mi) {
      #pragma unroll
      for (int nc = 0; nc < 2; ++nc) {
        f32x4 p;
        #pragma unroll
        for (int r = 0; r < 4; ++r) p[r] = exp2f(sacc[mi][nc][r] - mnew[mi][r]);
        rs[mi] += p;
        #pragma unroll
        for (int r = 0; r < 4; ++r) {
          int row  = qq * 32 + mi * 16 + g * 4 + r;
          int slot = (kvh * 4 + nc * 2 + (lr >> 3)) ^ ((g * 2 + (r >> 1)) & 7);
          *(_Float16*)(pbuf + row * 128 + slot * 16 + ((lr & 7) << 1)) = (_Float16)p[r];
        }
      }
    }
    #pragma unroll
    for (int m = 1; m < 16; m <<= 1) {
      rs[0] += shfl_xor4(rs[0], m);
      rs[1] += shfl_xor4(rs[1], m);
    }
    if (lr == 0) {
      #pragma unroll
      for (int mi = 0; mi < 2; ++mi)
        #pragma unroll
        for (int r = 0; r < 4; ++r)
          psumb[kvh * 128 + qq * 32 + mi * 16 + g * 4 + r] = rs[mi][r];
    }
    __syncthreads();  // B2: P + alf + partial sums visible

    #pragma unroll
    for (int mi = 0; mi < 2; ++mi) {
      f32x4 s0 = *(const f32x4*)(psumb + qq * 32 + mi * 16 + g * 4);
      f32x4 s1 = *(const f32x4*)(psumb + 128 + qq * 32 + mi * 16 + g * 4);
      lrow[mi] = lrow[mi] * al[mi] + (s0 + s1);
    }

    // ---- PV: rescale O by alpha, accumulate P[64q] x V[64d]
    #pragma unroll
    for (int mi = 0; mi < 4; ++mi) {
      f32x4 av = *(const f32x4*)(alf + qh * 64 + mi * 16 + g * 4);
      #pragma unroll
      for (int dc = 0; dc < 4; ++dc) o[mi][dc] *= av;
    }
    #pragma unroll
    for (int kc2 = 0; kc2 < 2; ++kc2) {
      half8 pf[4];
      #pragma unroll
      for (int mi = 0; mi < 4; ++mi)
        pf[mi] = *(const half8*)(pbuf + (qh * 64 + mi * 16 + lr) * 128 +
                                 (((kc2 * 4 + g) ^ ((lr >> 1) & 7)) << 4));
      #pragma unroll
      for (int dc = 0; dc < 4; ++dc) {
        half8 vf = *(const half8*)(vb + (dq * 64 + dc * 16 + lr) * 128 +
                                   (((kc2 * 4 + g) ^ (lr & 7)) << 4));
        #pragma unroll
        for (int mi = 0; mi < 4; ++mi)
          o[mi][dc] = __builtin_amdgcn_mfma_f32_16x16x32_f16(pf[mi], vf, o[mi][dc], 0, 0, 0);
      }
    }
    __syncthreads();  // B3: all reads of buf[cur] done before t+1 restages it
  }

  // ---- finalize: publish 1/l, normalize, stage O in LDS, coalesced store
  if (kvh == 0 && lr == 0) {
    #pragma unroll
    for (int mi = 0; mi < 2; ++mi)
      #pragma unroll
      for (int r = 0; r < 4; ++r)
        alf[qq * 32 + mi * 16 + g * 4 + r] = 1.0f / lrow[mi][r];
  }
  __syncthreads();
  _Float16* oL = (_Float16*)smem;  // [128][256] f16 = 64KB over K buffers
  #pragma unroll
  for (int mi = 0; mi < 4; ++mi) {
    f32x4 lv = *(const f32x4*)(alf + qh * 64 + mi * 16 + g * 4);
    #pragma unroll
    for (int dc = 0; dc < 4; ++dc) {
      #pragma unroll
      for (int r = 0; r < 4; ++r)
        oL[(qh * 64 + mi * 16 + g * 4 + r) * 256 + dq * 64 + dc * 16 + lr] =
            (_Float16)(o[mi][dc][r] * lv[r]);
    }
  }
  __syncthreads();
  #pragma unroll
  for (int i = 0; i < 8; ++i) {
    int p = i * 512 + tid;
    int row = p >> 5, sl = p & 31;   // 128 rows x 32 slots x 8 halves
    *(half8*)(og + ((size_t)(b * NSEQ + n0 + row)) * CDIM + sl * 8) =
        *(const half8*)(oL + row * 256 + sl * 8);
  }
}

// ---------------- launcher
extern "C" void kernel_launch(void* const* d_in, const int* in_sizes, int n_in,
                              void* d_out, int out_size, void* d_ws, size_t ws_size,
                              hipStream_t stream) {
  const float* x   = (const float*)d_in[0];
  const float* gam = (const float*)d_in[1];
  const float* bet = (const float*)d_in[2];
  const float* wq  = (const float*)d_in[3];
  const float* bq  = (const float*)d_in[4];
  const float* wk  = (const float*)d_in[5];
  const float* bk  = (const float*)d_in[6];
  const float* wv  = (const float*)d_in[7];
  const float* bv  = (const float*)d_in[8];
  const float* wp  = (const float*)d_in[9];
  const float* bp  = (const float*)d_in[10];
  float* out = (float*)d_out;

  char* ws = (char*)d_ws;
  float*    xnf = (float*)ws;                             // 32MB fp32 xn (residual)
  _Float16* xnh = (_Float16*)(ws + (32u << 20));          // 16MB f16 xn
  _Float16* qh  = (_Float16*)(ws + (48u << 20));          // 16MB q (scaled)
  _Float16* kh  = (_Float16*)(ws + (64u << 20));          // 16MB k
  _Float16* vth = (_Float16*)(ws + (80u << 20));          // 16MB v^T [b][c][n]
  _Float16* oh  = (_Float16*)(ws + (96u << 20));          // 16MB attn out

  (void)hipFuncSetAttribute((const void*)proj_kernel,
                            hipFuncAttributeMaxDynamicSharedMemorySize, 65536);
  (void)hipFuncSetAttribute((const void*)attn_kernel,
                            hipFuncAttributeMaxDynamicSharedMemorySize, ATTN_LDS);

  ln_kernel<<<NTOK / 4, 256, 0, stream>>>(x, gam, bet, xnf, xnh);
  proj_kernel<<<dim3(64, 4, 3), 256, 65536, stream>>>(
      xnh, wq, bq, wk, bk, wv, bv, wp, bp, qh, kh, vth, xnf, out, 0);
  attn_kernel<<<256, 512, ATTN_LDS, stream>>>(qh, kh, vth, oh);
  proj_kernel<<<dim3(64, 4, 1), 256, 65536, stream>>>(
      oh, wq, bq, wk, bk, wv, bv, wp, bp, qh, kh, vth, xnf, out, 3);
}

// Round 8
// 277.929 us; speedup vs baseline: 1.6754x; 1.2802x over previous
//
#include <hip/hip_runtime.h>
#include <cstdint>

#define NB    8
#define NSEQ  4096
#define CDIM  256
#define NTOK  (NB*NSEQ)

typedef _Float16 half8  __attribute__((ext_vector_type(8)));
typedef _Float16 half4v __attribute__((ext_vector_type(4)));
typedef float    f32x4  __attribute__((ext_vector_type(4)));
typedef float    f32x16 __attribute__((ext_vector_type(16)));
typedef uint32_t u32x4  __attribute__((ext_vector_type(4)));

typedef unsigned int u32_g __attribute__((address_space(1)));
typedef unsigned int u32_l __attribute__((address_space(3)));

// direct global->LDS, 16B per lane; LDS dest = wave-uniform base + lane*16
__device__ __forceinline__ void gload_lds16(const void* g, void* l) {
  __builtin_amdgcn_global_load_lds((u32_g*)(uintptr_t)g,
                                   (u32_l*)(uint32_t)(uintptr_t)l, 16, 0, 0);
}

__device__ __forceinline__ uint32_t pkrtz(float a, float b) {
  auto h = __builtin_amdgcn_cvt_pkrtz(a, b);  // lo16 = a, hi16 = b
  return __builtin_bit_cast(uint32_t, h);
}
// lane^32 exchange via shfl (semantics-certain)
__device__ __forceinline__ float sx32f(float v) { return __shfl_xor(v, 32, 64); }
__device__ __forceinline__ uint32_t sx32u(uint32_t v) {
  return (uint32_t)__shfl_xor((int)v, 32, 64);
}

// ---------------- LayerNorm: one wave per token (C=256 = 64 lanes x float4)
__global__ __launch_bounds__(256) void ln_kernel(
    const float* __restrict__ x, const float* __restrict__ gam,
    const float* __restrict__ bet, float* __restrict__ xnf,
    _Float16* __restrict__ xnh) {
  const int lane = threadIdx.x & 63;
  const size_t tok = (size_t)blockIdx.x * 4 + (threadIdx.x >> 6);
  const float4 v = ((const float4*)(x + tok * CDIM))[lane];
  float s  = v.x + v.y + v.z + v.w;
  float s2 = v.x*v.x + v.y*v.y + v.z*v.z + v.w*v.w;
  #pragma unroll
  for (int m = 1; m < 64; m <<= 1) {
    s  += __shfl_xor(s,  m, 64);
    s2 += __shfl_xor(s2, m, 64);
  }
  const float mean = s * (1.0f / CDIM);
  const float rstd = rsqrtf(s2 * (1.0f / CDIM) - mean * mean + 1e-3f);
  const float4 gv = ((const float4*)gam)[lane];
  const float4 bv = ((const float4*)bet)[lane];
  float4 o;
  o.x = (v.x - mean) * rstd * gv.x + bv.x;
  o.y = (v.y - mean) * rstd * gv.y + bv.y;
  o.z = (v.z - mean) * rstd * gv.z + bv.z;
  o.w = (v.w - mean) * rstd * gv.w + bv.w;
  ((float4*)(xnf + tok * CDIM))[lane] = o;
  half4v h;
  h[0] = (_Float16)o.x; h[1] = (_Float16)o.y;
  h[2] = (_Float16)o.z; h[3] = (_Float16)o.w;
  ((half4v*)(xnh + tok * CDIM))[lane] = h;
}

// ---------------- projection GEMM (unchanged from R1)
__global__ __launch_bounds__(256, 2) void proj_kernel(
    const _Float16* __restrict__ inh,
    const float* __restrict__ wq_, const float* __restrict__ bq_,
    const float* __restrict__ wk_, const float* __restrict__ bk_,
    const float* __restrict__ wv_, const float* __restrict__ bv_,
    const float* __restrict__ wp_, const float* __restrict__ bp_,
    _Float16* __restrict__ qg, _Float16* __restrict__ kg, _Float16* __restrict__ vtg,
    const float* __restrict__ xnf, float* __restrict__ outf,
    int mode_base) {
  extern __shared__ char smem[];
  const int mode = mode_base + blockIdx.z;
  const float* wsel = (mode == 0) ? wq_ : (mode == 1) ? wk_ : (mode == 2) ? wv_ : wp_;
  const float* bsel = (mode == 0) ? bq_ : (mode == 1) ? bk_ : (mode == 2) ? bv_ : bp_;

  const int tid = threadIdx.x;
  const int lane = tid & 63;
  const int wid  = tid >> 6;     // 0..3
  const int g    = lane >> 4;    // 0..3
  const int lr   = lane & 15;
  const int jstrip = blockIdx.y; // 0..3
  const size_t tok0 = (size_t)blockIdx.x * 512;

  char* wt   = smem;             // [64 j][256 c] f16, XOR-swizzled (32KB)
  char* tile = smem + 32768;     // [64 tok][256 c] f16, swizzled (32KB)

  for (int i = 0; i < 64; ++i) {
    int idx = i * 256 + tid;
    int c = idx >> 6, j = idx & 63;
    float val = wsel[(size_t)c * CDIM + jstrip * 64 + j];
    *(_Float16*)(wt + j * 512 + ((((c >> 3) ^ (j & 7))) << 4) + ((c & 7) << 1)) =
        (_Float16)val;
  }
  float bjv[4];
  #pragma unroll
  for (int jc = 0; jc < 4; ++jc) bjv[jc] = bsel[jstrip * 64 + jc * 16 + lr];
  __syncthreads();

  for (int t = 0; t < 8; ++t) {
    const size_t trow0 = tok0 + t * 64;
    #pragma unroll
    for (int i = 0; i < 8; ++i) {
      int pbase = (i * 4 + wid) * 64;
      int p = pbase + lane;
      int row = p >> 5, sl = p & 31;
      gload_lds16(inh + (trow0 + row) * CDIM + (size_t)((sl ^ (row & 7)) * 8),
                  tile + pbase * 16);
    }
    __syncthreads();

    f32x4 acc[4] = {{0,0,0,0},{0,0,0,0},{0,0,0,0},{0,0,0,0}};
    #pragma unroll
    for (int kc = 0; kc < 8; ++kc) {
      half8 a = *(const half8*)(tile + (wid * 16 + lr) * 512 +
                                ((((kc << 2) | g) ^ (lr & 7)) << 4));
      #pragma unroll
      for (int jc = 0; jc < 4; ++jc) {
        half8 bf = *(const half8*)(wt + (jc * 16 + lr) * 512 +
                                   ((((kc << 2) | g) ^ (lr & 7)) << 4));
        acc[jc] = __builtin_amdgcn_mfma_f32_16x16x32_f16(a, bf, acc[jc], 0, 0, 0);
      }
    }

    if (mode == 3) {
      #pragma unroll
      for (int jc = 0; jc < 4; ++jc) {
        #pragma unroll
        for (int r = 0; r < 4; ++r) {
          size_t row = trow0 + wid * 16 + g * 4 + r;
          size_t off = row * CDIM + jstrip * 64 + jc * 16 + lr;
          outf[off] = acc[jc][r] + bjv[jc] + xnf[off];
        }
      }
    } else {
      const float csc = (mode == 0) ? 0.09016844005556021f : 1.0f; // log2(e)/16
      __syncthreads();
      _Float16* ot = (_Float16*)tile;  // [64][72]
      #pragma unroll
      for (int jc = 0; jc < 4; ++jc)
        #pragma unroll
        for (int r = 0; r < 4; ++r)
          ot[(wid * 16 + g * 4 + r) * 72 + jc * 16 + lr] =
              (_Float16)((acc[jc][r] + bjv[jc]) * csc);
      __syncthreads();
      if (mode != 2) {
        _Float16* dst = (mode == 0) ? qg : kg;
        #pragma unroll
        for (int it = 0; it < 2; ++it) {
          int s = it * 256 + tid;
          int row = s >> 3, sl = s & 7;
          half8 vv = *(const half8*)(ot + row * 72 + sl * 8);
          *(half8*)(dst + (trow0 + row) * CDIM + jstrip * 64 + sl * 8) = vv;
        }
      } else {
        #pragma unroll
        for (int it = 0; it < 2; ++it) {
          int s = it * 256 + tid;
          int j = s >> 3, ns = s & 7;
          half8 vv;
          #pragma unroll
          for (int e = 0; e < 8; ++e) vv[e] = ot[(ns * 8 + e) * 72 + j];
          size_t bb  = trow0 >> 12;
          size_t nin = (trow0 & 4095) + ns * 8;
          *(half8*)(vtg + ((size_t)bb * CDIM + jstrip * 64 + j) * NSEQ + nin) = vv;
        }
      }
    }
    __syncthreads();
  }
}

// ---------------- flash attention v6: swapped-QK^T, 32x32 MFMA
// R7 + epilogue fix: o[dt][r] rows are q=crow(r,hi), NOT q=l31 -> the merge
// factor asel (per-lane, q=l31) must be SHUFFLED to lane q, exactly like rlt.
// R6/R7's identical absmax 3.08 came from this wrong per-row scaling.
// LDS: K0 @0, K1 @32K, V0 @64K, V1 @96K, mbuf @128K, lbuf @129K = 133120 B.
#define ATTN_LDS 133120

__global__ __launch_bounds__(512)
__attribute__((amdgpu_waves_per_eu(2, 2)))
void attn_kernel(
    const _Float16* __restrict__ qg, const _Float16* __restrict__ kg,
    const _Float16* __restrict__ vtg, _Float16* __restrict__ og) {
  extern __shared__ char smem[];
  float* mb = (float*)(smem + 131072);  // [8 waves][32 q]
  float* lb = (float*)(smem + 132096);  // [8 waves][32 q]

  const int tid  = threadIdx.x;
  const int lane = tid & 63;
  const int wid  = tid >> 6;    // 0..7
  const int l31  = lane & 31;
  const int hi   = lane >> 5;   // 0/1
  const int qg_  = wid & 3;     // q-group (32 rows)
  const int kvh  = wid >> 2;    // kv half of each 64-tile
  const int b    = blockIdx.x & 7;        // XCD-affine batch
  const int n0   = (blockIdx.x >> 3) * 128;

  // ---- prologue: stage tile 0 (K + V^T) into buffer 0
  #pragma unroll
  for (int i = 0; i < 4; ++i) {
    int pbase = (i * 8 + wid) * 64;
    int p = pbase + lane;
    int row = p >> 5, sl = p & 31;
    gload_lds16(kg + ((size_t)(b * NSEQ + row)) * CDIM + (sl ^ (row & 7)) * 8,
                smem + pbase * 16);
    int d = p >> 3, vsl = p & 7;
    gload_lds16(vtg + ((size_t)(b * CDIM + d)) * NSEQ + (vsl ^ (d & 7)) * 8,
                smem + 65536 + pbase * 16);
  }

  // ---- Q fragments: B-operand of swapped MFMA. lane holds Q[q=l31][c=ks*16+hi*8+j]
  half8 qf[16];
  {
    const _Float16* qp =
        qg + ((size_t)(b * NSEQ + n0 + qg_ * 32 + l31)) * CDIM + hi * 8;
    #pragma unroll
    for (int ks = 0; ks < 16; ++ks) qf[ks] = *(const half8*)(qp + ks * 16);
  }

  f32x16 o[8];  // O[q=(r&3)+8*(r>>2)+4*hi][d=dt*32+l31], f32
  #pragma unroll
  for (int dt = 0; dt < 8; ++dt)
    #pragma unroll
    for (int r = 0; r < 16; ++r) o[dt][r] = 0.0f;
  float mrun = -1e30f, lrun = 0.0f;

  __syncthreads();  // prologue staging drained

  const int krow = kvh * 32 + l31;
  const int kxor = krow & 7;

  for (int t = 0; t < 64; ++t) {
    const int cur = t & 1;
    const char* kb = smem + cur * 32768;
    const char* vb = smem + 65536 + cur * 32768;

    // issue next tile's staging into the other buffer (drained at iter-end barrier)
    if (t < 63) {
      const int kv0n = (t + 1) * 64;
      char* kn = smem + (cur ^ 1) * 32768;
      char* vn = smem + 65536 + (cur ^ 1) * 32768;
      #pragma unroll
      for (int i = 0; i < 4; ++i) {
        int pbase = (i * 8 + wid) * 64;
        int p = pbase + lane;
        int row = p >> 5, sl = p & 31;
        gload_lds16(kg + ((size_t)(b * NSEQ + kv0n + row)) * CDIM + (sl ^ (row & 7)) * 8,
                    kn + pbase * 16);
        int d = p >> 3, vsl = p & 7;
        gload_lds16(vtg + ((size_t)(b * CDIM + d)) * NSEQ + kv0n + (vsl ^ (d & 7)) * 8,
                    vn + pbase * 16);
      }
    }

    // ---- S^T = K x Q^T : one 32x32 C-tile/wave (32 kv x 32 q), 16 k-steps
    f32x16 sacc;
    #pragma unroll
    for (int r = 0; r < 16; ++r) sacc[r] = 0.0f;
    const char* krowp = kb + krow * 512;
    #pragma unroll
    for (int ks = 0; ks < 16; ++ks) {
      half8 kf = *(const half8*)(krowp + (((ks * 2 + hi) ^ kxor) << 4));
      sacc = __builtin_amdgcn_mfma_f32_32x32x16_f16(kf, qf[ks], sacc, 0, 0, 0);
    }

    // ---- in-register online softmax (col q = l31; sacc[r] = S^T[kv=crow(r,hi)][q])
    float pm = sacc[0];
    #pragma unroll
    for (int r = 1; r < 16; ++r) pm = fmaxf(pm, sacc[r]);
    pm = fmaxf(pm, sx32f(pm));  // full 32-kv row max for this tile

    if (!__all(pm - mrun <= 8.0f)) {   // defer-max (T13), THR=8 in log2 domain
      float mnew = fmaxf(mrun, pm);
      float al = exp2f(mrun - mnew);
      mrun = mnew;
      lrun *= al;
      #pragma unroll
      for (int r = 0; r < 16; ++r) {
        float ar = __shfl(al, (r & 3) + 8 * (r >> 2) + 4 * hi, 64);
        #pragma unroll
        for (int dt = 0; dt < 8; ++dt) o[dt][r] *= ar;
      }
    }

    float p[16], ls = 0.0f;
    #pragma unroll
    for (int r = 0; r < 16; ++r) { p[r] = exp2f(sacc[r] - mrun); ls += p[r]; }
    lrun += ls + sx32f(ls);

    // ---- pack P -> f16 A-frags: cvt_pkrtz + lane^32 shfl + select
    uint32_t c01 = pkrtz(p[0],  p[1]),  c23 = pkrtz(p[2],  p[3]);
    uint32_t c45 = pkrtz(p[4],  p[5]),  c67 = pkrtz(p[6],  p[7]);
    uint32_t c89 = pkrtz(p[8],  p[9]),  cab = pkrtz(p[10], p[11]);
    uint32_t ccd = pkrtz(p[12], p[13]), cef = pkrtz(p[14], p[15]);
    uint32_t t01 = sx32u(c01), t23 = sx32u(c23);
    uint32_t t45 = sx32u(c45), t67 = sx32u(c67);
    uint32_t t89 = sx32u(c89), tab = sx32u(cab);
    uint32_t tcd = sx32u(ccd), tef = sx32u(cef);
    half8 pa0 = __builtin_bit_cast(half8, (u32x4){
        hi ? t45 : c01, hi ? t67 : c23, hi ? c45 : t01, hi ? c67 : t23});
    half8 pa1 = __builtin_bit_cast(half8, (u32x4){
        hi ? tcd : c89, hi ? tef : cab, hi ? ccd : t89, hi ? cef : tab});

    // ---- PV: O[32q x 256d] += P[32q x 32kv] x V[32kv x 256d]
    #pragma unroll
    for (int dt = 0; dt < 8; ++dt) {
      const char* vrow = vb + (dt * 32 + l31) * 128;
      const int vx = (dt * 32 + l31) & 7;
      half8 vf0 = *(const half8*)(vrow + (((kvh * 4 + 0 + hi) ^ vx) << 4));
      half8 vf1 = *(const half8*)(vrow + (((kvh * 4 + 2 + hi) ^ vx) << 4));
      o[dt] = __builtin_amdgcn_mfma_f32_32x32x16_f16(pa0, vf0, o[dt], 0, 0, 0);
      o[dt] = __builtin_amdgcn_mfma_f32_32x32x16_f16(pa1, vf1, o[dt], 0, 0, 0);
    }

    __syncthreads();  // reads of buf[cur] done + staging into buf[cur^1] drained
  }

  // ---- epilogue: merge the two kv-half waves (wid, wid^4) via LDS
  if (lane < 32) mb[wid * 32 + lane] = mrun;
  __syncthreads();
  float mo = mb[(wid ^ 4) * 32 + l31];
  float M  = fmaxf(mrun, mo);
  float asel = exp2f(mrun - M);   // per-lane: factor for q = l31
  if (lane < 32) lb[wid * 32 + lane] = lrun * asel;
  __syncthreads();
  float lt = lrun * asel + lb[(wid ^ 4) * 32 + l31];
  float rlt = 1.0f / lt;          // per-lane: 1/l for q = l31

  float* ob = (float*)smem + (size_t)(wid & 3) * 8192;  // [32 q][256 d] f32 per pair
  if (wid >= 4) {
    #pragma unroll
    for (int r = 0; r < 16; ++r) {
      int q = (r & 3) + 8 * (r >> 2) + 4 * hi;
      float aq = __shfl(asel, q, 64);          // FIX: factor for row q, not l31
      #pragma unroll
      for (int dt = 0; dt < 8; ++dt)
        ob[q * 256 + dt * 32 + l31] = o[dt][r] * aq;
    }
  }
  __syncthreads();
  if (wid < 4) {
    #pragma unroll
    for (int r = 0; r < 16; ++r) {
      int q = (r & 3) + 8 * (r >> 2) + 4 * hi;
      float aq = __shfl(asel, q, 64);          // FIX: factor for row q
      float rq = __shfl(rlt, q, 64);
      #pragma unroll
      for (int dt = 0; dt < 8; ++dt) {
        float v = o[dt][r] * aq + ob[q * 256 + dt * 32 + l31];
        og[((size_t)(b * NSEQ + n0 + qg_ * 32 + q)) * CDIM + dt * 32 + l31] =
            (_Float16)(v * rq);
      }
    }
  }
}

// ---------------- launcher
extern "C" void kernel_launch(void* const* d_in, const int* in_sizes, int n_in,
                              void* d_out, int out_size, void* d_ws, size_t ws_size,
                              hipStream_t stream) {
  const float* x   = (const float*)d_in[0];
  const float* gam = (const float*)d_in[1];
  const float* bet = (const float*)d_in[2];
  const float* wq  = (const float*)d_in[3];
  const float* bq  = (const float*)d_in[4];
  const float* wk  = (const float*)d_in[5];
  const float* bk  = (const float*)d_in[6];
  const float* wv  = (const float*)d_in[7];
  const float* bv  = (const float*)d_in[8];
  const float* wp  = (const float*)d_in[9];
  const float* bp  = (const float*)d_in[10];
  float* out = (float*)d_out;

  char* ws = (char*)d_ws;
  float*    xnf = (float*)ws;                             // 32MB fp32 xn (residual)
  _Float16* xnh = (_Float16*)(ws + (32u << 20));          // 16MB f16 xn
  _Float16* qh  = (_Float16*)(ws + (48u << 20));          // 16MB q (scaled)
  _Float16* kh  = (_Float16*)(ws + (64u << 20));          // 16MB k
  _Float16* vth = (_Float16*)(ws + (80u << 20));          // 16MB v^T [b][c][n]
  _Float16* oh  = (_Float16*)(ws + (96u << 20));          // 16MB attn out

  (void)hipFuncSetAttribute((const void*)proj_kernel,
                            hipFuncAttributeMaxDynamicSharedMemorySize, 65536);
  (void)hipFuncSetAttribute((const void*)attn_kernel,
                            hipFuncAttributeMaxDynamicSharedMemorySize, ATTN_LDS);

  ln_kernel<<<NTOK / 4, 256, 0, stream>>>(x, gam, bet, xnf, xnh);
  proj_kernel<<<dim3(64, 4, 3), 256, 65536, stream>>>(
      xnh, wq, bq, wk, bk, wv, bv, wp, bp, qh, kh, vth, xnf, out, 0);
  attn_kernel<<<256, 512, ATTN_LDS, stream>>>(qh, kh, vth, oh);
  proj_kernel<<<dim3(64, 4, 1), 256, 65536, stream>>>(
      oh, wq, bq, wk, bk, wv, bv, wp, bp, qh, kh, vth, xnf, out, 3);
}